// Round 10
// baseline (167.155 us; speedup 1.0000x reference)
//
#include <hip/hip_runtime.h>
#include <stdint.h>

// Problem constants (fixed by the reference)
#define B_IMG        64
#define M_GT         100
#define N_PROP       4000
#define K_TOT        4100          // N + M (proposal_append_gt)
#define NUM_CLASSES_ 80
#define BATCH_PER    512
#define NUM_FG_TGT   128
#define OUT_STRIDE   (B_IMG * BATCH_PER)   // 32768 elements per output tensor

#define NTH          1024                  // threads per block
#define HALF_CAP     1024                  // candidate capacity per group (fg | bg)
#define QPI          8                     // producer blocks (slices) per image
#define SLICE        513                   // ceil(K_TOT / QPI); last block gets 509
#define PAIRS        (NTH / 2)             // element-pairs per block iteration
#define CTR_STRIDE   64                    // words between ctr[b] (256 B: own line)
#define CTR_BYTES    (B_IMG * CTR_STRIDE * 4)   // 16 KiB

// Key packing (uint64 compare gives exact (fg, pri, idx) descending order;
// midx rides in the low bits — idx is unique so it never affects ordering):
//   bit 50      : fg flag
//   bits 49..20 : float bits of priority (pri in [0,1) => bits < 2^30)
//   bits 19..7  : element index (0..4099 < 8192)  — reproduces the reversed-
//                 stable-argsort tiebreak (higher idx first on equal pri)
//   bits  6..0  : matched gt index (0..99 < 128)

// IoU with contraction disabled so float32 results match the numpy reference
// bit-for-bit. area_a computed in-register with the identical expression.
__device__ __forceinline__ float iou_g(float4 g,
                                       float bx1, float by1, float bx2, float by2,
                                       float area_b) {
#pragma clang fp contract(off)
    float area_a = (g.z - g.x) * (g.w - g.y);
    float ltx = fmaxf(g.x, bx1), lty = fmaxf(g.y, by1);
    float rbx = fminf(g.z, bx2), rby = fminf(g.w, by2);
    float wx = fmaxf(rbx - ltx, 0.0f);
    float wy = fmaxf(rby - lty, 0.0f);
    float inter = wx * wy;
    float uni = area_a + area_b - inter;
    return inter > 0.0f ? inter / uni : 0.0f;
}

// ---------------------------------------------------------------------------
// Fused chip-wide kernel (R9 winner + three changes):
//  (a) 2-lane m-split in phase A: lanes (2e,2e+1) scan m in [0,50)/[50,100)
//      for the same element, combined with one __shfl_xor — doubles the
//      concurrent division-chains per SIMD (the one-thread-per-element
//      decomposition is capped at 4 chains/SIMD chip-wide) and halves the
//      chain length. Combine rule (take upper half only on strict >) is
//      exactly sequential first-occurrence argmax.
//  (b) ctr[b] padded to its own 256 B line — 64 spinners + producers no
//      longer contend on shared coherent lines.
//  (c) phase-B key loads are plain cached loads again (R5-proven correct
//      after the acquire fence); stores stay agent-scope coherent so the
//      release has no dirty L2 to drain (the R9 win).
// Grid = B_IMG*QPI = 512 blocks x 1024 threads = exactly 2 blocks/CU
// co-resident (64 KB LDS x2 <= 160 KB; VGPR<=64 via launch bounds).
// ---------------------------------------------------------------------------
__global__ __launch_bounds__(NTH, 8) void fused_kernel(
        const float* __restrict__ gt_boxes,    // [B, M, 4]
        const float* __restrict__ prop_boxes,  // [B, N, 4]
        const int*   __restrict__ gt_classes,  // [B, M]
        const float* __restrict__ rand_pri,    // [B, K]
        uint64_t*    __restrict__ keys,        // [B, K] in ws (after ctr region)
        uint32_t*    __restrict__ ctr,         // [B*CTR_STRIDE] arrival ctrs (zeroed)
        float*       __restrict__ out)         // 5 x [B, 512] flat
{
    __shared__ uint64_t s_keys[K_TOT];         // 32.8 KB (owner phase B)
    __shared__ uint64_t s_cand[2 * HALF_CAP];  // 16 KB: fg half | bg half
    __shared__ int      s_hist[2][256];        // 2 KB
    __shared__ float4   s_gtb4[M_GT];          // 1.6 KB gt boxes as float4
    __shared__ int      s_gtc[M_GT];
    __shared__ float    s_out[5][BATCH_PER];   // 10 KB staging
    __shared__ int      s_T[2], s_needed[2], s_cnt[2];

    const int blk = blockIdx.x;
    const int b   = blk >> 3;                  // image
    const int q   = blk & 7;                   // slice
    const int tid = threadIdx.x;

    // ---- stage gt data for image b ----
    for (int i = tid; i < M_GT; i += NTH)
        s_gtb4[i] = ((const float4*)gt_boxes)[(size_t)b * M_GT + i];
    for (int i = tid; i < M_GT; i += NTH)
        s_gtc[i] = gt_classes[(size_t)b * M_GT + i];
    __syncthreads();

    // ---- phase A: IoU argmax + key build, 2 lanes per element ----
    const int qstart = q * SLICE;
    const int qend   = min(qstart + SLICE, K_TOT);
    const int half   = tid & 1;                // 0: m in [0,50), 1: m in [50,100)
    const int mlo    = half * (M_GT / 2);
    // uniform trip count (ceil(513/512) = 2) so shuffles see full exec mask
    for (int it = 0; it < 2; ++it) {
        const int pe  = qstart + it * PAIRS + (tid >> 1);
        const bool val = pe < qend;
        const int pes = val ? pe : qstart;     // safe address for inactive pairs
        const uint32_t pb = __float_as_uint(rand_pri[(size_t)b * K_TOT + pes]);
        float bx1, by1, bx2, by2;
        if (pes < N_PROP) {
            const float4 bp = *(const float4*)(prop_boxes + ((size_t)b * N_PROP + pes) * 4);
            bx1 = bp.x; by1 = bp.y; bx2 = bp.z; by2 = bp.w;
        } else {
            const float4 bp = s_gtb4[pes - N_PROP];
            bx1 = bp.x; by1 = bp.y; bx2 = bp.z; by2 = bp.w;
        }
        float area_b;
        {
#pragma clang fp contract(off)
            area_b = (bx2 - bx1) * (by2 - by1);
        }
        float best = -1.0f; int bidx = mlo;
        for (int m = mlo; m < mlo + M_GT / 2; ++m) {
            float iv = iou_g(s_gtb4[m], bx1, by1, bx2, by2, area_b);
            if (iv > best) { best = iv; bidx = m; }  // strict > => first max in half
        }
        // combine halves: upper wins only on strict > (== sequential argmax)
        const float ob = __shfl_xor(best, 1);
        const int   oi = __shfl_xor(bidx, 1);
        if (half == 0) {
            if (ob > best) { best = ob; bidx = oi; }
            if (val) {
                const bool fg = best >= 0.5f;
                uint64_t key = (fg ? (1ull << 50) : 0ull)
                             | ((uint64_t)pb << 20)
                             | ((uint64_t)pe << 7)
                             | (uint64_t)bidx;
                // coherent (L2-bypassing) store: nothing dirty for the release
                __hip_atomic_store(&keys[(size_t)b * K_TOT + pe], key,
                                   __ATOMIC_RELAXED, __HIP_MEMORY_SCOPE_AGENT);
            }
        }
    }
    __syncthreads();
    if (tid == 0)    // release orders the atomic key stores before the arrival
        __hip_atomic_fetch_add(&ctr[b * CTR_STRIDE], 1u,
                               __ATOMIC_RELEASE, __HIP_MEMORY_SCOPE_AGENT);
    if (q != 0) return;                         // non-owner producers done

    // ---- owner: relaxed spin for all 8 producers, then one acquire fence ----
    if (tid == 0) {
        while (__hip_atomic_load(&ctr[b * CTR_STRIDE],
                                 __ATOMIC_RELAXED, __HIP_MEMORY_SCOPE_AGENT) < (uint32_t)QPI)
            __builtin_amdgcn_s_sleep(2);
    }
    __syncthreads();
    __builtin_amdgcn_fence(__ATOMIC_ACQUIRE, "agent");   // invalidates stale L1/L2

    // ---- phase B: stage keys (plain cached loads) + histogram per group ----
    for (int i = tid; i < 512; i += NTH) s_hist[i >> 8][i & 255] = 0;
    if (tid < 2) s_cnt[tid] = 0;
    __syncthreads();
    for (int k = tid; k < K_TOT; k += NTH) {
        uint64_t key = keys[(size_t)b * K_TOT + k];
        s_keys[k] = key;
        int g = ((key >> 50) & 1ull) ? 0 : 1;   // 0 = fg, 1 = bg
        uint32_t pbits = (uint32_t)((key >> 20) & 0x3FFFFFFFull);
        int bucket = min(255, (int)(__uint_as_float(pbits) * 256.0f));  // monotone
        atomicAdd(&s_hist[g][bucket], 1);
    }
    __syncthreads();

    // Hillis-Steele suffix scan over each 256-bucket histogram
    for (int d = 1; d < 256; d <<= 1) {
        int v = 0, g = tid >> 8, t = tid & 255;
        bool act = (tid < 512) && (t + d < 256);
        if (act) v = s_hist[g][t + d];
        __syncthreads();
        if (act) s_hist[g][t] += v;
        __syncthreads();
    }

    if (tid == 0) {
        int fg_total = s_hist[0][0];
        int bg_total = s_hist[1][0];
        int nfg = min(NUM_FG_TGT, fg_total);
        int nbg = min(BATCH_PER - nfg, bg_total);
        s_needed[0] = nfg; s_needed[1] = nbg;
    }
    __syncthreads();

    // bucket threshold: max t with S[t] >= need (unique crossing; S non-increasing)
    if (tid < 512) {
        int g = tid >> 8, t = tid & 255;
        int need = s_needed[g];
        int St  = s_hist[g][t];
        int St1 = (t == 255) ? -1 : s_hist[g][t + 1];
        if (St >= need && St1 < need) s_T[g] = t;
    }
    if (tid < BATCH_PER) {                     // prefill invalid pattern
        s_out[0][tid] = 0.0f; s_out[1][tid] = -1.0f;
        s_out[2][tid] = -1.0f; s_out[3][tid] = -1.0f;
    }
    __syncthreads();

    const int nfg = s_needed[0], nbg = s_needed[1];
    if (tid < BATCH_PER)
        s_out[4][tid] = (tid < nfg + nbg) ? 1.0f : 0.0f;

    // compaction into disjoint halves (fg -> [0,HALF_CAP), bg -> [HALF_CAP,...))
    for (int k = tid; k < K_TOT; k += NTH) {
        uint64_t key = s_keys[k];
        int g = ((key >> 50) & 1ull) ? 0 : 1;
        uint32_t pbits = (uint32_t)((key >> 20) & 0x3FFFFFFFull);
        int bucket = min(255, (int)(__uint_as_float(pbits) * 256.0f));
        if (bucket >= s_T[g]) {
            int pos = atomicAdd(&s_cnt[g], 1);
            if (pos < HALF_CAP) s_cand[g * HALF_CAP + pos] = key;
        }
    }
    __syncthreads();

    // rank within each half (keys unique -> each slot written exactly once,
    // independent of atomic ordering) and emit
    const int fgc = min(s_cnt[0], HALF_CAP);
    const int bgc = min(s_cnt[1], HALF_CAP);
    for (int c = tid; c < fgc + bgc; c += NTH) {
        const bool isfg = (c < fgc);
        const int  base = isfg ? 0 : HALF_CAP;
        const int  cnt  = isfg ? fgc : bgc;
        const int  ci   = isfg ? c : (c - fgc);
        const uint64_t kc = s_cand[base + ci];
        int r = 0;
        for (int j = 0; j < cnt; ++j)          // broadcast LDS reads
            r += (s_cand[base + j] > kc) ? 1 : 0;
        int slot = -1;
        if (isfg) { if (r < nfg) slot = r; }
        else      { if (r < nbg) slot = nfg + r; }
        if (slot >= 0) {
            int idx = (int)((kc >> 7) & 0x1FFFull);
            int mi  = (int)(kc & 0x7Full);
            float bx1, by1, bx2, by2;
            if (idx < N_PROP) {
                const float4 bp = *(const float4*)(prop_boxes + ((size_t)b * N_PROP + idx) * 4);
                bx1 = bp.x; by1 = bp.y; bx2 = bp.z; by2 = bp.w;
            } else {
                const float4 bp = s_gtb4[idx - N_PROP];
                bx1 = bp.x; by1 = bp.y; bx2 = bp.z; by2 = bp.w;
            }
            float area_b;
            {
#pragma clang fp contract(off)
                area_b = (bx2 - bx1) * (by2 - by1);
            }
            // bit-exact matched_vals[idx]: same fp ops on same inputs as phase A
            float iou = iou_g(s_gtb4[mi], bx1, by1, bx2, by2, area_b);
            s_out[0][slot] = iou;
            s_out[1][slot] = (float)idx;
            s_out[2][slot] = (float)(isfg ? s_gtc[mi] : NUM_CLASSES_);
            s_out[3][slot] = (float)mi;
        }
    }
    __syncthreads();

    // coalesced write-out
    for (int i = tid; i < 5 * BATCH_PER; i += NTH) {
        int o = i / BATCH_PER, p = i % BATCH_PER;
        out[(size_t)o * OUT_STRIDE + (size_t)b * BATCH_PER + p] = s_out[o][p];
    }
}

// ---------------------------------------------------------------------------
// Fallback: proven single kernel (one block per image, zero workspace).
// Used only if ws_size is too small for the key buffer + counters.
// ---------------------------------------------------------------------------
__global__ __launch_bounds__(NTH) void roiheads_fallback(
        const float* __restrict__ gt_boxes,
        const float* __restrict__ prop_boxes,
        const int*   __restrict__ gt_classes,
        const float* __restrict__ rand_pri,
        float*       __restrict__ out)
{
    __shared__ uint64_t s_keys[K_TOT];
    __shared__ uint64_t s_cand[2 * HALF_CAP];
    __shared__ int      s_hist[2][256];
    __shared__ float4   s_gtb4[M_GT];
    __shared__ int      s_gtc[M_GT];
    __shared__ float    s_out[5][BATCH_PER];
    __shared__ int      s_T[2], s_needed[2], s_cnt[2];

    const int b   = blockIdx.x;
    const int tid = threadIdx.x;

    for (int i = tid; i < 512; i += NTH) s_hist[i >> 8][i & 255] = 0;
    if (tid < 2) s_cnt[tid] = 0;
    for (int i = tid; i < M_GT; i += NTH)
        s_gtb4[i] = ((const float4*)gt_boxes)[(size_t)b * M_GT + i];
    for (int i = tid; i < M_GT; i += NTH)
        s_gtc[i] = gt_classes[(size_t)b * M_GT + i];
    __syncthreads();

    for (int k = tid; k < K_TOT; k += NTH) {
        float bx1, by1, bx2, by2;
        if (k < N_PROP) {
            const float4 bp = *(const float4*)(prop_boxes + ((size_t)b * N_PROP + k) * 4);
            bx1 = bp.x; by1 = bp.y; bx2 = bp.z; by2 = bp.w;
        } else {
            const float4 bp = s_gtb4[k - N_PROP];
            bx1 = bp.x; by1 = bp.y; bx2 = bp.z; by2 = bp.w;
        }
        float area_b;
        {
#pragma clang fp contract(off)
            area_b = (bx2 - bx1) * (by2 - by1);
        }
        float best = -1.0f; int bidx = 0;
        for (int m = 0; m < M_GT; ++m) {
            float iv = iou_g(s_gtb4[m], bx1, by1, bx2, by2, area_b);
            if (iv > best) { best = iv; bidx = m; }
        }
        const bool fg = best >= 0.5f;
        const float pri = rand_pri[(size_t)b * K_TOT + k];
        const uint32_t pb = __float_as_uint(pri);
        s_keys[k] = (fg ? (1ull << 50) : 0ull)
                  | ((uint64_t)pb << 20)
                  | ((uint64_t)k  << 7)
                  | (uint64_t)bidx;
        int bucket = min(255, (int)(pri * 256.0f));
        atomicAdd(&s_hist[fg ? 0 : 1][bucket], 1);
    }
    __syncthreads();

    for (int d = 1; d < 256; d <<= 1) {
        int v = 0, g = tid >> 8, t = tid & 255;
        bool act = (tid < 512) && (t + d < 256);
        if (act) v = s_hist[g][t + d];
        __syncthreads();
        if (act) s_hist[g][t] += v;
        __syncthreads();
    }

    if (tid == 0) {
        int fg_total = s_hist[0][0];
        int bg_total = s_hist[1][0];
        int nfg = min(NUM_FG_TGT, fg_total);
        int nbg = min(BATCH_PER - nfg, bg_total);
        s_needed[0] = nfg; s_needed[1] = nbg;
    }
    __syncthreads();

    if (tid < 512) {
        int g = tid >> 8, t = tid & 255;
        int need = s_needed[g];
        int St  = s_hist[g][t];
        int St1 = (t == 255) ? -1 : s_hist[g][t + 1];
        if (St >= need && St1 < need) s_T[g] = t;
    }
    if (tid < BATCH_PER) {
        s_out[0][tid] = 0.0f; s_out[1][tid] = -1.0f;
        s_out[2][tid] = -1.0f; s_out[3][tid] = -1.0f;
    }
    __syncthreads();

    const int nfg = s_needed[0], nbg = s_needed[1];
    if (tid < BATCH_PER)
        s_out[4][tid] = (tid < nfg + nbg) ? 1.0f : 0.0f;

    for (int k = tid; k < K_TOT; k += NTH) {
        uint64_t key = s_keys[k];
        int g = ((key >> 50) & 1ull) ? 0 : 1;
        uint32_t pbits = (uint32_t)((key >> 20) & 0x3FFFFFFFull);
        int bucket = min(255, (int)(__uint_as_float(pbits) * 256.0f));
        if (bucket >= s_T[g]) {
            int pos = atomicAdd(&s_cnt[g], 1);
            if (pos < HALF_CAP) s_cand[g * HALF_CAP + pos] = key;
        }
    }
    __syncthreads();

    const int fgc = min(s_cnt[0], HALF_CAP);
    const int bgc = min(s_cnt[1], HALF_CAP);
    for (int c = tid; c < fgc + bgc; c += NTH) {
        const bool isfg = (c < fgc);
        const int  base = isfg ? 0 : HALF_CAP;
        const int  cnt  = isfg ? fgc : bgc;
        const int  ci   = isfg ? c : (c - fgc);
        const uint64_t kc = s_cand[base + ci];
        int r = 0;
        for (int j = 0; j < cnt; ++j)
            r += (s_cand[base + j] > kc) ? 1 : 0;
        int slot = -1;
        if (isfg) { if (r < nfg) slot = r; }
        else      { if (r < nbg) slot = nfg + r; }
        if (slot >= 0) {
            int idx = (int)((kc >> 7) & 0x1FFFull);
            int mi  = (int)(kc & 0x7Full);
            float bx1, by1, bx2, by2;
            if (idx < N_PROP) {
                const float4 bp = *(const float4*)(prop_boxes + ((size_t)b * N_PROP + idx) * 4);
                bx1 = bp.x; by1 = bp.y; bx2 = bp.z; by2 = bp.w;
            } else {
                const float4 bp = s_gtb4[idx - N_PROP];
                bx1 = bp.x; by1 = bp.y; bx2 = bp.z; by2 = bp.w;
            }
            float area_b;
            {
#pragma clang fp contract(off)
                area_b = (bx2 - bx1) * (by2 - by1);
            }
            float iou = iou_g(s_gtb4[mi], bx1, by1, bx2, by2, area_b);
            s_out[0][slot] = iou;
            s_out[1][slot] = (float)idx;
            s_out[2][slot] = (float)(isfg ? s_gtc[mi] : NUM_CLASSES_);
            s_out[3][slot] = (float)mi;
        }
    }
    __syncthreads();

    for (int i = tid; i < 5 * BATCH_PER; i += NTH) {
        int o = i / BATCH_PER, p = i % BATCH_PER;
        out[(size_t)o * OUT_STRIDE + (size_t)b * BATCH_PER + p] = s_out[o][p];
    }
}

extern "C" void kernel_launch(void* const* d_in, const int* in_sizes, int n_in,
                              void* d_out, int out_size, void* d_ws, size_t ws_size,
                              hipStream_t stream) {
    const float* gt_boxes   = (const float*)d_in[0];  // [64,100,4]
    const float* prop_boxes = (const float*)d_in[1];  // [64,4000,4]
    const int*   gt_classes = (const int*)  d_in[2];  // [64,100]
    const float* rand_pri   = (const float*)d_in[3];  // [64,4100]
    float* out = (float*)d_out;                       // 5 x [64,512] float32, concat

    const size_t need_ws = CTR_BYTES + (size_t)B_IMG * K_TOT * sizeof(uint64_t);
    if (d_ws != nullptr && ws_size >= need_ws) {
        uint32_t* ctr  = (uint32_t*)d_ws;
        uint64_t* keys = (uint64_t*)((char*)d_ws + CTR_BYTES);
        // zero arrival counters (captured into the graph, ordered on stream)
        hipMemsetAsync(d_ws, 0, CTR_BYTES, stream);
        fused_kernel<<<B_IMG * QPI, NTH, 0, stream>>>(gt_boxes, prop_boxes,
                                                      gt_classes, rand_pri,
                                                      keys, ctr, out);
    } else {
        roiheads_fallback<<<B_IMG, NTH, 0, stream>>>(gt_boxes, prop_boxes,
                                                     gt_classes, rand_pri, out);
    }
}

// Round 11
// 126.090 us; speedup vs baseline: 1.3257x; 1.3257x over previous
//
#include <hip/hip_runtime.h>
#include <stdint.h>

// Problem constants (fixed by the reference)
#define B_IMG        64
#define M_GT         100
#define N_PROP       4000
#define K_TOT        4100          // N + M (proposal_append_gt)
#define NUM_CLASSES_ 80
#define BATCH_PER    512
#define NUM_FG_TGT   128
#define OUT_STRIDE   (B_IMG * BATCH_PER)   // 32768 elements per output tensor

#define NTH          1024                  // threads per block
#define HALF_CAP     1024                  // candidate capacity per group (fg | bg)
#define QPI          5                     // producer blocks (slices) per image
#define SLICE        820                   // 5 * 820 == 4100 exactly (uniform)
#define CTR_STRIDE   64                    // words between ctr[b] (256 B: own line)
#define CTR_BYTES    (B_IMG * CTR_STRIDE * 4)   // 16 KiB

// Key packing (uint64 compare gives exact (fg, pri, idx) descending order;
// midx rides in the low bits — idx is unique so it never affects ordering):
//   bit 50      : fg flag
//   bits 49..20 : float bits of priority (pri in [0,1) => bits < 2^30)
//   bits 19..7  : element index (0..4099 < 8192)  — reproduces the reversed-
//                 stable-argsort tiebreak (higher idx first on equal pri)
//   bits  6..0  : matched gt index (0..99 < 128)

// IoU with contraction disabled so float32 results match the numpy reference
// bit-for-bit. area_a computed in-register with the identical expression.
__device__ __forceinline__ float iou_g(float4 g,
                                       float bx1, float by1, float bx2, float by2,
                                       float area_b) {
#pragma clang fp contract(off)
    float area_a = (g.z - g.x) * (g.w - g.y);
    float ltx = fmaxf(g.x, bx1), lty = fmaxf(g.y, by1);
    float rbx = fminf(g.z, bx2), rby = fminf(g.w, by2);
    float wx = fmaxf(rbx - ltx, 0.0f);
    float wy = fmaxf(rby - lty, 0.0f);
    float inter = wx * wy;
    float uni = area_a + area_b - inter;
    return inter > 0.0f ? inter / uni : 0.0f;
}

// ---------------------------------------------------------------------------
// Fused chip-wide kernel (R9 winner + two changes, both targeting the
// measured ~53 us owner tail):
//  (a) LAST-ARRIVER OWNERSHIP: no dedicated spinning owner. Each producer
//      release-adds ctr[b]; the block whose add returns QPI-1 becomes the
//      owner, acquire-fences, and runs phase B immediately. Zero spin time,
//      and the kernel is deadlock-free regardless of block residency (no
//      block ever waits on another). Phase-B output is independent of which
//      block owns (keys complete, gt data staged in every block).
//  (b) uniform slicing QPI=5 x SLICE=820 (= 4100 exactly): one m-loop pass
//      per thread — removes R9's wave-0 double-pass (+25% critical path).
// Transport (the R9 win): key stores are agent-scope coherent so the
// release drains no dirty L2; phase-B loads are plain cached (post-fence).
// Grid = B_IMG*QPI = 320 blocks x 1024 threads.
// ---------------------------------------------------------------------------
__global__ __launch_bounds__(NTH, 8) void fused_kernel(
        const float* __restrict__ gt_boxes,    // [B, M, 4]
        const float* __restrict__ prop_boxes,  // [B, N, 4]
        const int*   __restrict__ gt_classes,  // [B, M]
        const float* __restrict__ rand_pri,    // [B, K]
        uint64_t*    __restrict__ keys,        // [B, K] in ws (after ctr region)
        uint32_t*    __restrict__ ctr,         // [B*CTR_STRIDE] arrival ctrs (zeroed)
        float*       __restrict__ out)         // 5 x [B, 512] flat
{
    __shared__ uint64_t s_keys[K_TOT];         // 32.8 KB (owner phase B)
    __shared__ uint64_t s_cand[2 * HALF_CAP];  // 16 KB: fg half | bg half
    __shared__ int      s_hist[2][256];        // 2 KB
    __shared__ float4   s_gtb4[M_GT];          // 1.6 KB gt boxes as float4
    __shared__ int      s_gtc[M_GT];
    __shared__ float    s_out[5][BATCH_PER];   // 10 KB staging
    __shared__ int      s_T[2], s_needed[2], s_cnt[2];
    __shared__ int      s_owner;

    const int blk = blockIdx.x;
    const int b   = blk / QPI;                 // image
    const int q   = blk % QPI;                 // slice
    const int tid = threadIdx.x;

    // ---- stage gt data for image b ----
    for (int i = tid; i < M_GT; i += NTH)
        s_gtb4[i] = ((const float4*)gt_boxes)[(size_t)b * M_GT + i];
    for (int i = tid; i < M_GT; i += NTH)
        s_gtc[i] = gt_classes[(size_t)b * M_GT + i];
    __syncthreads();

    // ---- phase A: IoU argmax + key build for slice q (one pass, uniform) ----
    if (tid < SLICE) {
        const int k = q * SLICE + tid;         // 5*820 == 4100: always < K_TOT
        const uint32_t pb = __float_as_uint(rand_pri[(size_t)b * K_TOT + k]);
        float bx1, by1, bx2, by2;
        if (k < N_PROP) {
            const float4 bp = *(const float4*)(prop_boxes + ((size_t)b * N_PROP + k) * 4);
            bx1 = bp.x; by1 = bp.y; bx2 = bp.z; by2 = bp.w;
        } else {
            const float4 bp = s_gtb4[k - N_PROP];
            bx1 = bp.x; by1 = bp.y; bx2 = bp.z; by2 = bp.w;
        }
        float area_b;
        {
#pragma clang fp contract(off)
            area_b = (bx2 - bx1) * (by2 - by1);
        }
        float best = -1.0f; int bidx = 0;
        for (int m = 0; m < M_GT; ++m) {
            float iv = iou_g(s_gtb4[m], bx1, by1, bx2, by2, area_b);  // ds_read_b128
            if (iv > best) { best = iv; bidx = m; }  // strict > => first-occurrence argmax
        }
        const bool fg = best >= 0.5f;
        uint64_t key = (fg ? (1ull << 50) : 0ull)
                     | ((uint64_t)pb << 20)
                     | ((uint64_t)k  << 7)
                     | (uint64_t)bidx;
        // coherent (L2-bypassing) store: nothing dirty left for the release
        __hip_atomic_store(&keys[(size_t)b * K_TOT + k], key,
                           __ATOMIC_RELAXED, __HIP_MEMORY_SCOPE_AGENT);
    }
    __syncthreads();

    // ---- arrival: last block to arrive for image b becomes the owner ----
    if (tid == 0) {
        uint32_t old = __hip_atomic_fetch_add(&ctr[b * CTR_STRIDE], 1u,
                                              __ATOMIC_RELEASE, __HIP_MEMORY_SCOPE_AGENT);
        s_owner = (old == (uint32_t)(QPI - 1)) ? 1 : 0;
    }
    __syncthreads();
    if (!s_owner) return;                      // non-owners exit immediately
    __builtin_amdgcn_fence(__ATOMIC_ACQUIRE, "agent");   // sync with all releases

    // ---- phase B: stage keys (plain cached loads) + histogram per group ----
    for (int i = tid; i < 512; i += NTH) s_hist[i >> 8][i & 255] = 0;
    if (tid < 2) s_cnt[tid] = 0;
    __syncthreads();
    for (int k = tid; k < K_TOT; k += NTH) {
        uint64_t key = keys[(size_t)b * K_TOT + k];
        s_keys[k] = key;
        int g = ((key >> 50) & 1ull) ? 0 : 1;   // 0 = fg, 1 = bg
        uint32_t pbits = (uint32_t)((key >> 20) & 0x3FFFFFFFull);
        int bucket = min(255, (int)(__uint_as_float(pbits) * 256.0f));  // monotone
        atomicAdd(&s_hist[g][bucket], 1);
    }
    __syncthreads();

    // Hillis-Steele suffix scan over each 256-bucket histogram
    for (int d = 1; d < 256; d <<= 1) {
        int v = 0, g = tid >> 8, t = tid & 255;
        bool act = (tid < 512) && (t + d < 256);
        if (act) v = s_hist[g][t + d];
        __syncthreads();
        if (act) s_hist[g][t] += v;
        __syncthreads();
    }

    if (tid == 0) {
        int fg_total = s_hist[0][0];
        int bg_total = s_hist[1][0];
        int nfg = min(NUM_FG_TGT, fg_total);
        int nbg = min(BATCH_PER - nfg, bg_total);
        s_needed[0] = nfg; s_needed[1] = nbg;
    }
    __syncthreads();

    // bucket threshold: max t with S[t] >= need (unique crossing; S non-increasing)
    if (tid < 512) {
        int g = tid >> 8, t = tid & 255;
        int need = s_needed[g];
        int St  = s_hist[g][t];
        int St1 = (t == 255) ? -1 : s_hist[g][t + 1];
        if (St >= need && St1 < need) s_T[g] = t;
    }
    if (tid < BATCH_PER) {                     // prefill invalid pattern
        s_out[0][tid] = 0.0f; s_out[1][tid] = -1.0f;
        s_out[2][tid] = -1.0f; s_out[3][tid] = -1.0f;
    }
    __syncthreads();

    const int nfg = s_needed[0], nbg = s_needed[1];
    if (tid < BATCH_PER)
        s_out[4][tid] = (tid < nfg + nbg) ? 1.0f : 0.0f;

    // compaction into disjoint halves (fg -> [0,HALF_CAP), bg -> [HALF_CAP,...))
    for (int k = tid; k < K_TOT; k += NTH) {
        uint64_t key = s_keys[k];
        int g = ((key >> 50) & 1ull) ? 0 : 1;
        uint32_t pbits = (uint32_t)((key >> 20) & 0x3FFFFFFFull);
        int bucket = min(255, (int)(__uint_as_float(pbits) * 256.0f));
        if (bucket >= s_T[g]) {
            int pos = atomicAdd(&s_cnt[g], 1);
            if (pos < HALF_CAP) s_cand[g * HALF_CAP + pos] = key;
        }
    }
    __syncthreads();

    // rank within each half (keys unique -> each slot written exactly once,
    // independent of atomic ordering) and emit
    const int fgc = min(s_cnt[0], HALF_CAP);
    const int bgc = min(s_cnt[1], HALF_CAP);
    for (int c = tid; c < fgc + bgc; c += NTH) {
        const bool isfg = (c < fgc);
        const int  base = isfg ? 0 : HALF_CAP;
        const int  cnt  = isfg ? fgc : bgc;
        const int  ci   = isfg ? c : (c - fgc);
        const uint64_t kc = s_cand[base + ci];
        int r = 0;
        for (int j = 0; j < cnt; ++j)          // broadcast LDS reads
            r += (s_cand[base + j] > kc) ? 1 : 0;
        int slot = -1;
        if (isfg) { if (r < nfg) slot = r; }
        else      { if (r < nbg) slot = nfg + r; }
        if (slot >= 0) {
            int idx = (int)((kc >> 7) & 0x1FFFull);
            int mi  = (int)(kc & 0x7Full);
            float bx1, by1, bx2, by2;
            if (idx < N_PROP) {
                const float4 bp = *(const float4*)(prop_boxes + ((size_t)b * N_PROP + idx) * 4);
                bx1 = bp.x; by1 = bp.y; bx2 = bp.z; by2 = bp.w;
            } else {
                const float4 bp = s_gtb4[idx - N_PROP];
                bx1 = bp.x; by1 = bp.y; bx2 = bp.z; by2 = bp.w;
            }
            float area_b;
            {
#pragma clang fp contract(off)
                area_b = (bx2 - bx1) * (by2 - by1);
            }
            // bit-exact matched_vals[idx]: same fp ops on same inputs as phase A
            float iou = iou_g(s_gtb4[mi], bx1, by1, bx2, by2, area_b);
            s_out[0][slot] = iou;
            s_out[1][slot] = (float)idx;
            s_out[2][slot] = (float)(isfg ? s_gtc[mi] : NUM_CLASSES_);
            s_out[3][slot] = (float)mi;
        }
    }
    __syncthreads();

    // coalesced write-out
    for (int i = tid; i < 5 * BATCH_PER; i += NTH) {
        int o = i / BATCH_PER, p = i % BATCH_PER;
        out[(size_t)o * OUT_STRIDE + (size_t)b * BATCH_PER + p] = s_out[o][p];
    }
}

// ---------------------------------------------------------------------------
// Fallback: proven single kernel (one block per image, zero workspace).
// Used only if ws_size is too small for the key buffer + counters.
// ---------------------------------------------------------------------------
__global__ __launch_bounds__(NTH) void roiheads_fallback(
        const float* __restrict__ gt_boxes,
        const float* __restrict__ prop_boxes,
        const int*   __restrict__ gt_classes,
        const float* __restrict__ rand_pri,
        float*       __restrict__ out)
{
    __shared__ uint64_t s_keys[K_TOT];
    __shared__ uint64_t s_cand[2 * HALF_CAP];
    __shared__ int      s_hist[2][256];
    __shared__ float4   s_gtb4[M_GT];
    __shared__ int      s_gtc[M_GT];
    __shared__ float    s_out[5][BATCH_PER];
    __shared__ int      s_T[2], s_needed[2], s_cnt[2];

    const int b   = blockIdx.x;
    const int tid = threadIdx.x;

    for (int i = tid; i < 512; i += NTH) s_hist[i >> 8][i & 255] = 0;
    if (tid < 2) s_cnt[tid] = 0;
    for (int i = tid; i < M_GT; i += NTH)
        s_gtb4[i] = ((const float4*)gt_boxes)[(size_t)b * M_GT + i];
    for (int i = tid; i < M_GT; i += NTH)
        s_gtc[i] = gt_classes[(size_t)b * M_GT + i];
    __syncthreads();

    for (int k = tid; k < K_TOT; k += NTH) {
        float bx1, by1, bx2, by2;
        if (k < N_PROP) {
            const float4 bp = *(const float4*)(prop_boxes + ((size_t)b * N_PROP + k) * 4);
            bx1 = bp.x; by1 = bp.y; bx2 = bp.z; by2 = bp.w;
        } else {
            const float4 bp = s_gtb4[k - N_PROP];
            bx1 = bp.x; by1 = bp.y; bx2 = bp.z; by2 = bp.w;
        }
        float area_b;
        {
#pragma clang fp contract(off)
            area_b = (bx2 - bx1) * (by2 - by1);
        }
        float best = -1.0f; int bidx = 0;
        for (int m = 0; m < M_GT; ++m) {
            float iv = iou_g(s_gtb4[m], bx1, by1, bx2, by2, area_b);
            if (iv > best) { best = iv; bidx = m; }
        }
        const bool fg = best >= 0.5f;
        const float pri = rand_pri[(size_t)b * K_TOT + k];
        const uint32_t pb = __float_as_uint(pri);
        s_keys[k] = (fg ? (1ull << 50) : 0ull)
                  | ((uint64_t)pb << 20)
                  | ((uint64_t)k  << 7)
                  | (uint64_t)bidx;
        int bucket = min(255, (int)(pri * 256.0f));
        atomicAdd(&s_hist[fg ? 0 : 1][bucket], 1);
    }
    __syncthreads();

    for (int d = 1; d < 256; d <<= 1) {
        int v = 0, g = tid >> 8, t = tid & 255;
        bool act = (tid < 512) && (t + d < 256);
        if (act) v = s_hist[g][t + d];
        __syncthreads();
        if (act) s_hist[g][t] += v;
        __syncthreads();
    }

    if (tid == 0) {
        int fg_total = s_hist[0][0];
        int bg_total = s_hist[1][0];
        int nfg = min(NUM_FG_TGT, fg_total);
        int nbg = min(BATCH_PER - nfg, bg_total);
        s_needed[0] = nfg; s_needed[1] = nbg;
    }
    __syncthreads();

    if (tid < 512) {
        int g = tid >> 8, t = tid & 255;
        int need = s_needed[g];
        int St  = s_hist[g][t];
        int St1 = (t == 255) ? -1 : s_hist[g][t + 1];
        if (St >= need && St1 < need) s_T[g] = t;
    }
    if (tid < BATCH_PER) {
        s_out[0][tid] = 0.0f; s_out[1][tid] = -1.0f;
        s_out[2][tid] = -1.0f; s_out[3][tid] = -1.0f;
    }
    __syncthreads();

    const int nfg = s_needed[0], nbg = s_needed[1];
    if (tid < BATCH_PER)
        s_out[4][tid] = (tid < nfg + nbg) ? 1.0f : 0.0f;

    for (int k = tid; k < K_TOT; k += NTH) {
        uint64_t key = s_keys[k];
        int g = ((key >> 50) & 1ull) ? 0 : 1;
        uint32_t pbits = (uint32_t)((key >> 20) & 0x3FFFFFFFull);
        int bucket = min(255, (int)(__uint_as_float(pbits) * 256.0f));
        if (bucket >= s_T[g]) {
            int pos = atomicAdd(&s_cnt[g], 1);
            if (pos < HALF_CAP) s_cand[g * HALF_CAP + pos] = key;
        }
    }
    __syncthreads();

    const int fgc = min(s_cnt[0], HALF_CAP);
    const int bgc = min(s_cnt[1], HALF_CAP);
    for (int c = tid; c < fgc + bgc; c += NTH) {
        const bool isfg = (c < fgc);
        const int  base = isfg ? 0 : HALF_CAP;
        const int  cnt  = isfg ? fgc : bgc;
        const int  ci   = isfg ? c : (c - fgc);
        const uint64_t kc = s_cand[base + ci];
        int r = 0;
        for (int j = 0; j < cnt; ++j)
            r += (s_cand[base + j] > kc) ? 1 : 0;
        int slot = -1;
        if (isfg) { if (r < nfg) slot = r; }
        else      { if (r < nbg) slot = nfg + r; }
        if (slot >= 0) {
            int idx = (int)((kc >> 7) & 0x1FFFull);
            int mi  = (int)(kc & 0x7Full);
            float bx1, by1, bx2, by2;
            if (idx < N_PROP) {
                const float4 bp = *(const float4*)(prop_boxes + ((size_t)b * N_PROP + idx) * 4);
                bx1 = bp.x; by1 = bp.y; bx2 = bp.z; by2 = bp.w;
            } else {
                const float4 bp = s_gtb4[idx - N_PROP];
                bx1 = bp.x; by1 = bp.y; bx2 = bp.z; by2 = bp.w;
            }
            float area_b;
            {
#pragma clang fp contract(off)
                area_b = (bx2 - bx1) * (by2 - by1);
            }
            float iou = iou_g(s_gtb4[mi], bx1, by1, bx2, by2, area_b);
            s_out[0][slot] = iou;
            s_out[1][slot] = (float)idx;
            s_out[2][slot] = (float)(isfg ? s_gtc[mi] : NUM_CLASSES_);
            s_out[3][slot] = (float)mi;
        }
    }
    __syncthreads();

    for (int i = tid; i < 5 * BATCH_PER; i += NTH) {
        int o = i / BATCH_PER, p = i % BATCH_PER;
        out[(size_t)o * OUT_STRIDE + (size_t)b * BATCH_PER + p] = s_out[o][p];
    }
}

extern "C" void kernel_launch(void* const* d_in, const int* in_sizes, int n_in,
                              void* d_out, int out_size, void* d_ws, size_t ws_size,
                              hipStream_t stream) {
    const float* gt_boxes   = (const float*)d_in[0];  // [64,100,4]
    const float* prop_boxes = (const float*)d_in[1];  // [64,4000,4]
    const int*   gt_classes = (const int*)  d_in[2];  // [64,100]
    const float* rand_pri   = (const float*)d_in[3];  // [64,4100]
    float* out = (float*)d_out;                       // 5 x [64,512] float32, concat

    const size_t need_ws = CTR_BYTES + (size_t)B_IMG * K_TOT * sizeof(uint64_t);
    if (d_ws != nullptr && ws_size >= need_ws) {
        uint32_t* ctr  = (uint32_t*)d_ws;
        uint64_t* keys = (uint64_t*)((char*)d_ws + CTR_BYTES);
        // zero arrival counters (captured into the graph, ordered on stream)
        hipMemsetAsync(d_ws, 0, CTR_BYTES, stream);
        fused_kernel<<<B_IMG * QPI, NTH, 0, stream>>>(gt_boxes, prop_boxes,
                                                      gt_classes, rand_pri,
                                                      keys, ctr, out);
    } else {
        roiheads_fallback<<<B_IMG, NTH, 0, stream>>>(gt_boxes, prop_boxes,
                                                     gt_classes, rand_pri, out);
    }
}